// Round 1
// baseline (66.920 us; speedup 1.0000x reference)
//
#include <hip/hip_runtime.h>
#include <math.h>

// Problem geometry (fixed by the reference):
//   env    : (B=2, 16, 32, 3)  f32
//   normal : (B, 512, 512, 3)  f32
//   albedo : (B, 3, 512, 512)  f32
//   out    : (B, 3, 512, 512)  f32
// out[b,c,y,x] = (1/50) * albedo[b,c,y,x] *
//                sum_m relu(n(b,y,x) . l_m) * env[b,i,j,c]*sin(phi_i)
// where n = (normal[...,::-1]-0.5)*2, m = i*32+j, l_m = unit dir.

constexpr int HDR_H = 16;
constexpr int HDR_W = 32;
constexpr int M     = HDR_H * HDR_W;   // 512 lights
constexpr int HW    = 512 * 512;
constexpr int BLOCK = 256;
constexpr int PIX_PER_THREAD = 2;      // amortize LDS broadcast reads

__global__ __launch_bounds__(BLOCK)
void env_render_kernel(const float* __restrict__ env,
                       const float* __restrict__ normal,
                       const float* __restrict__ albedo,
                       float* __restrict__ out)
{
    // [m][0] = light dir (x,y,z,0), [m][1] = hdr weights (r,g,b,0)
    __shared__ float4 tab[M][2];

    const int b   = blockIdx.y;
    const int tid = threadIdx.x;

    // --- Build the light table in LDS (2 lights per thread) ---
    for (int m = tid; m < M; m += BLOCK) {
        const int i = m >> 5;        // phi row
        const int j = m & 31;        // theta col
        const float phi   = ((float)i * (1.0f / 16.0f)) * 3.14159265358979323846f;
        const float theta = ((float)j * (1.0f / 32.0f)) * 6.28318530717958647692f;
        const float sp = sinf(phi),   cp = cosf(phi);
        const float st = sinf(theta), ct = cosf(theta);
        float d0 = st * sp;
        float d1 = cp;
        float d2 = -ct * sp;
        const float inv = rsqrtf(d0 * d0 + d1 * d1 + d2 * d2); // analytically 1
        tab[m][0] = make_float4(d0 * inv, d1 * inv, d2 * inv, 0.0f);
        const float* e = env + ((size_t)(b * HDR_H + i) * HDR_W + j) * 3;
        tab[m][1] = make_float4(e[0] * sp, e[1] * sp, e[2] * sp, 0.0f);
    }
    __syncthreads();

    // --- Each thread: PIX_PER_THREAD pixels vs all 512 lights ---
    const int pix0 = blockIdx.x * (BLOCK * PIX_PER_THREAD) + tid;

    float nx[PIX_PER_THREAD], ny[PIX_PER_THREAD], nz[PIX_PER_THREAD];
    float a0[PIX_PER_THREAD], a1[PIX_PER_THREAD], a2[PIX_PER_THREAD];

    #pragma unroll
    for (int k = 0; k < PIX_PER_THREAD; ++k) {
        const int pix = pix0 + k * BLOCK;
        const float* np_ = normal + ((size_t)b * HW + pix) * 3;
        // channel flip (::-1) then decode to [-1,1]
        nx[k] = (np_[2] - 0.5f) * 2.0f;
        ny[k] = (np_[1] - 0.5f) * 2.0f;
        nz[k] = (np_[0] - 0.5f) * 2.0f;
        a0[k] = a1[k] = a2[k] = 0.0f;
    }

    #pragma unroll 8
    for (int m = 0; m < M; ++m) {
        const float4 d = tab[m][0];  // broadcast (wave-uniform address)
        const float4 h = tab[m][1];
        #pragma unroll
        for (int k = 0; k < PIX_PER_THREAD; ++k) {
            float dot = fmaf(nx[k], d.x, fmaf(ny[k], d.y, nz[k] * d.z));
            dot = fmaxf(dot, 0.0f);
            a0[k] = fmaf(dot, h.x, a0[k]);
            a1[k] = fmaf(dot, h.y, a1[k]);
            a2[k] = fmaf(dot, h.z, a2[k]);
        }
    }

    const float s = 1.0f / 50.0f;
    #pragma unroll
    for (int k = 0; k < PIX_PER_THREAD; ++k) {
        const int pix = pix0 + k * BLOCK;
        const size_t base = (size_t)b * 3 * HW + pix;
        out[base]          = a0[k] * s * albedo[base];
        out[base + HW]     = a1[k] * s * albedo[base + HW];
        out[base + 2 * HW] = a2[k] * s * albedo[base + 2 * HW];
    }
}

extern "C" void kernel_launch(void* const* d_in, const int* in_sizes, int n_in,
                              void* d_out, int out_size, void* d_ws, size_t ws_size,
                              hipStream_t stream)
{
    const float* env    = (const float*)d_in[0];
    const float* normal = (const float*)d_in[1];
    const float* albedo = (const float*)d_in[2];
    float* out          = (float*)d_out;

    const int B = in_sizes[0] / (HDR_H * HDR_W * 3);   // = 2
    dim3 grid(HW / (BLOCK * PIX_PER_THREAD), B);       // (512, 2)
    env_render_kernel<<<grid, BLOCK, 0, stream>>>(env, normal, albedo, out);
}

// Round 2
// 45.287 us; speedup vs baseline: 1.4777x; 1.4777x over previous
//
#include <hip/hip_runtime.h>
#include <math.h>

// out[b,c,y,x] = (1/50) * albedo[b,c,y,x] * sum_m relu(n . l_m) * h_mc
//   n = (normal[...,::-1]-0.5)*2,  h_mc = env[b,i,j,c]*sin(phi_i)
// ReLU trick: sum_m relu(d)h = 0.5*( n.(sum l h^T) + sum |d| h )
//   -> inner loop needs only |dot| (abs = free operand modifier, no v_max)
//   -> 6 VALU instr / pixel / light; constants 0.5*(1/50)=0.01 folded into h.

constexpr int HDR_H = 16;
constexpr int HDR_W = 32;
constexpr int M     = HDR_H * HDR_W;   // 512 lights
constexpr int HW    = 512 * 512;
constexpr int BLOCK = 256;
constexpr int PPT   = 4;               // pixels per thread

__global__ __launch_bounds__(BLOCK)
void env_render_kernel(const float* __restrict__ env,
                       const float* __restrict__ normal,
                       const float* __restrict__ albedo,
                       float* __restrict__ out)
{
    __shared__ float4 tabA[M];             // dir.x, dir.y, dir.z, h.r   (h pre-scaled by 0.01)
    __shared__ float2 tabB[M];             // h.g, h.b
    __shared__ float  Wwave[BLOCK / 64][9];

    const int b   = blockIdx.y;
    const int tid = threadIdx.x;

    // --- Build light table + per-thread partial W = sum_m l_m h_m^T ---
    float W[9];
    #pragma unroll
    for (int q = 0; q < 9; ++q) W[q] = 0.0f;

    for (int m = tid; m < M; m += BLOCK) {
        const int i = m >> 5;              // phi row
        const int j = m & 31;              // theta col
        // phi = i*pi/16, theta = j*2pi/32 = j*pi/16
        const float phi   = (float)i * 0.19634954084936207f;
        const float theta = (float)j * 0.19634954084936207f;
        const float sp = sinf(phi),   cp = cosf(phi);
        const float st = sinf(theta), ct = cosf(theta);
        float dx = st * sp;
        float dy = cp;
        float dz = -ct * sp;
        const float inv = rsqrtf(dx * dx + dy * dy + dz * dz);  // analytically 1
        dx *= inv; dy *= inv; dz *= inv;
        const float* e = env + ((size_t)(b * HDR_H + i) * HDR_W + j) * 3;
        const float scale = sp * 0.01f;    // sin(phi) row coeff * 0.5 * (1/50)
        const float hr = e[0] * scale, hg = e[1] * scale, hb = e[2] * scale;
        tabA[m] = make_float4(dx, dy, dz, hr);
        tabB[m] = make_float2(hg, hb);
        W[0] = fmaf(dx, hr, W[0]); W[1] = fmaf(dx, hg, W[1]); W[2] = fmaf(dx, hb, W[2]);
        W[3] = fmaf(dy, hr, W[3]); W[4] = fmaf(dy, hg, W[4]); W[5] = fmaf(dy, hb, W[5]);
        W[6] = fmaf(dz, hr, W[6]); W[7] = fmaf(dz, hg, W[7]); W[8] = fmaf(dz, hb, W[8]);
    }

    // --- Reduce W across the block (wave shfl + LDS) ---
    #pragma unroll
    for (int q = 0; q < 9; ++q) {
        float v = W[q];
        #pragma unroll
        for (int off = 32; off > 0; off >>= 1) v += __shfl_down(v, off);
        if ((tid & 63) == 0) Wwave[tid >> 6][q] = v;
    }
    __syncthreads();
    #pragma unroll
    for (int q = 0; q < 9; ++q)
        W[q] = Wwave[0][q] + Wwave[1][q] + Wwave[2][q] + Wwave[3][q];

    // --- Main loop: PPT pixels vs all 512 lights ---
    const int pix0 = blockIdx.x * (BLOCK * PPT) + tid;

    float nx[PPT], ny[PPT], nz[PPT], s0[PPT], s1[PPT], s2[PPT];
    #pragma unroll
    for (int k = 0; k < PPT; ++k) {
        const int pix = pix0 + k * BLOCK;
        const float* p = normal + ((size_t)b * HW + pix) * 3;
        nx[k] = fmaf(p[2], 2.0f, -1.0f);   // channel flip + decode
        ny[k] = fmaf(p[1], 2.0f, -1.0f);
        nz[k] = fmaf(p[0], 2.0f, -1.0f);
        s0[k] = s1[k] = s2[k] = 0.0f;
    }

    #pragma unroll 8
    for (int m = 0; m < M; ++m) {
        const float4 A  = tabA[m];   // broadcast reads, conflict-free
        const float2 Bv = tabB[m];
        #pragma unroll
        for (int k = 0; k < PPT; ++k) {
            const float d = fmaf(nx[k], A.x, fmaf(ny[k], A.y, nz[k] * A.z));
            const float a = fabsf(d);                  // operand modifier
            s0[k] = fmaf(a, A.w,  s0[k]);
            s1[k] = fmaf(a, Bv.x, s1[k]);
            s2[k] = fmaf(a, Bv.y, s2[k]);
        }
    }

    // --- Epilogue: add linear term n.W, multiply albedo, store ---
    #pragma unroll
    for (int k = 0; k < PPT; ++k) {
        const int pix = pix0 + k * BLOCK;
        const size_t base = (size_t)b * 3 * HW + pix;
        const float l0 = s0[k] + fmaf(nx[k], W[0], fmaf(ny[k], W[3], nz[k] * W[6]));
        const float l1 = s1[k] + fmaf(nx[k], W[1], fmaf(ny[k], W[4], nz[k] * W[7]));
        const float l2 = s2[k] + fmaf(nx[k], W[2], fmaf(ny[k], W[5], nz[k] * W[8]));
        out[base]          = l0 * albedo[base];
        out[base + HW]     = l1 * albedo[base + HW];
        out[base + 2 * HW] = l2 * albedo[base + 2 * HW];
    }
}

extern "C" void kernel_launch(void* const* d_in, const int* in_sizes, int n_in,
                              void* d_out, int out_size, void* d_ws, size_t ws_size,
                              hipStream_t stream)
{
    const float* env    = (const float*)d_in[0];
    const float* normal = (const float*)d_in[1];
    const float* albedo = (const float*)d_in[2];
    float* out          = (float*)d_out;

    const int B = in_sizes[0] / (HDR_H * HDR_W * 3);   // = 2
    dim3 grid(HW / (BLOCK * PPT), B);                  // (256, 2)
    env_render_kernel<<<grid, BLOCK, 0, stream>>>(env, normal, albedo, out);
}

// Round 3
// 31.762 us; speedup vs baseline: 2.1069x; 1.4258x over previous
//
#include <hip/hip_runtime.h>
#include <math.h>

// out[b,c,y,x] = (1/50)*albedo[b,c,y,x] * sum_m relu(n.l_m)*env[b,i,j,c]*sin(phi_i)
//   n = (normal[...,::-1]-0.5)*2
//
// relu(d) = (d+|d|)/2, and lights pair antipodally:
//   (i,j) <-> (16-i,(j+16)&31) gives l' = -l with the SAME sin(phi) coeff.
//   => light = 0.01*( n.W + sum_{240 pairs} |n.l_p| * (h_a+h_b) ),
//      W = sum_pairs l_a (h_a-h_b)^T,  h = env*sin(phi),  0.01 = 0.5*(1/50).
// Row i=0 has sin(phi)=0 -> no contribution.
//
// Pair table + W precomputed into d_ws by build_tab_kernel; the main kernel
// reads them with wave-uniform indices (-> scalar s_load, no LDS pipe at all).

constexpr int HDR_H = 16;
constexpr int HDR_W = 32;
constexpr int NPAIR = 240;          // 7*32 (rows 1..7 vs 9..15) + 16 (row 8 self)
constexpr int HW    = 512 * 512;
constexpr int BLOCK = 256;
constexpr int PPT   = 4;

__global__ __launch_bounds__(256)
void build_tab_kernel(const float* __restrict__ env, float* __restrict__ ws, int B)
{
    const int b = blockIdx.x;
    const int t = threadIdx.x;
    float4* dirs = (float4*)ws;                              // [B][NPAIR] dir.xyz, hsum.r
    float2* hs   = (float2*)(ws + (size_t)B * NPAIR * 4);    // [B][NPAIR] hsum.gb
    float*  Wout = ws + (size_t)B * NPAIR * 6;               // [B][9]

    __shared__ float Wred[4][9];
    float W[9];
    #pragma unroll
    for (int q = 0; q < 9; ++q) W[q] = 0.0f;

    if (t < NPAIR) {
        int i, j;
        if (t < 224) { i = 1 + (t >> 5); j = t & 31; }       // rows 1..7, all j
        else         { i = 8;            j = t - 224; }      // row 8, j<16 (self-pair)
        const int i2 = 16 - i;
        const int j2 = (j + 16) & 31;
        const float phi   = (float)i * 0.19634954084936207f; // pi/16
        const float theta = (float)j * 0.19634954084936207f; // 2*pi/32
        const float sp = sinf(phi),   cp = cosf(phi);
        const float st = sinf(theta), ct = cosf(theta);
        float dx = st * sp, dy = cp, dz = -ct * sp;
        const float inv = rsqrtf(dx * dx + dy * dy + dz * dz);
        dx *= inv; dy *= inv; dz *= inv;
        const float scale = sp * 0.01f;                      // sin(phi)=sin(pi-phi), *0.5/50
        const float* ea = env + ((size_t)(b * HDR_H + i ) * HDR_W + j ) * 3;
        const float* eb = env + ((size_t)(b * HDR_H + i2) * HDR_W + j2) * 3;
        const float hsr = (ea[0] + eb[0]) * scale;
        const float hsg = (ea[1] + eb[1]) * scale;
        const float hsb = (ea[2] + eb[2]) * scale;
        const float hd0 = (ea[0] - eb[0]) * scale;
        const float hd1 = (ea[1] - eb[1]) * scale;
        const float hd2 = (ea[2] - eb[2]) * scale;
        dirs[b * NPAIR + t] = make_float4(dx, dy, dz, hsr);
        hs[b * NPAIR + t]   = make_float2(hsg, hsb);
        W[0] = dx * hd0; W[1] = dx * hd1; W[2] = dx * hd2;
        W[3] = dy * hd0; W[4] = dy * hd1; W[5] = dy * hd2;
        W[6] = dz * hd0; W[7] = dz * hd1; W[8] = dz * hd2;
    }
    #pragma unroll
    for (int q = 0; q < 9; ++q) {
        float v = W[q];
        #pragma unroll
        for (int off = 32; off > 0; off >>= 1) v += __shfl_down(v, off);
        if ((t & 63) == 0) Wred[t >> 6][q] = v;
    }
    __syncthreads();
    if (t < 9) Wout[b * 9 + t] = Wred[0][t] + Wred[1][t] + Wred[2][t] + Wred[3][t];
}

__global__ __launch_bounds__(BLOCK)
void env_render_kernel(const float* __restrict__ normal,
                       const float* __restrict__ albedo,
                       const float4* __restrict__ dirs,
                       const float2* __restrict__ hs,
                       const float* __restrict__ Wmat,
                       float* __restrict__ out)
{
    const int b   = blockIdx.y;
    const int tid = threadIdx.x;
    const float4* __restrict__ dirsb = dirs + b * NPAIR;
    const float2* __restrict__ hsb   = hs   + b * NPAIR;

    float Wl[9];
    #pragma unroll
    for (int q = 0; q < 9; ++q) Wl[q] = Wmat[b * 9 + q];     // uniform -> s_load

    const int pix0 = blockIdx.x * (BLOCK * PPT) + tid;

    float nx[PPT], ny[PPT], nz[PPT], s0[PPT], s1[PPT], s2[PPT];
    #pragma unroll
    for (int k = 0; k < PPT; ++k) {
        const int pix = pix0 + k * BLOCK;
        const float* p = normal + ((size_t)b * HW + pix) * 3;
        nx[k] = fmaf(p[2], 2.0f, -1.0f);                     // channel flip + decode
        ny[k] = fmaf(p[1], 2.0f, -1.0f);
        nz[k] = fmaf(p[0], 2.0f, -1.0f);
        s0[k] = s1[k] = s2[k] = 0.0f;
    }

    #pragma unroll 8
    for (int m = 0; m < NPAIR; ++m) {
        const float4 A = dirsb[m];                           // uniform -> s_load_dwordx4
        const float2 H = hsb[m];                             // uniform -> s_load_dwordx2
        #pragma unroll
        for (int k = 0; k < PPT; ++k) {
            const float d = fmaf(nx[k], A.x, fmaf(ny[k], A.y, nz[k] * A.z));
            const float a = fabsf(d);                        // free operand modifier
            s0[k] = fmaf(a, A.w, s0[k]);
            s1[k] = fmaf(a, H.x, s1[k]);
            s2[k] = fmaf(a, H.y, s2[k]);
        }
    }

    #pragma unroll
    for (int k = 0; k < PPT; ++k) {
        const int pix = pix0 + k * BLOCK;
        const size_t base = (size_t)b * 3 * HW + pix;
        const float l0 = s0[k] + fmaf(nx[k], Wl[0], fmaf(ny[k], Wl[3], nz[k] * Wl[6]));
        const float l1 = s1[k] + fmaf(nx[k], Wl[1], fmaf(ny[k], Wl[4], nz[k] * Wl[7]));
        const float l2 = s2[k] + fmaf(nx[k], Wl[2], fmaf(ny[k], Wl[5], nz[k] * Wl[8]));
        out[base]          = l0 * albedo[base];
        out[base + HW]     = l1 * albedo[base + HW];
        out[base + 2 * HW] = l2 * albedo[base + 2 * HW];
    }
}

extern "C" void kernel_launch(void* const* d_in, const int* in_sizes, int n_in,
                              void* d_out, int out_size, void* d_ws, size_t ws_size,
                              hipStream_t stream)
{
    const float* env    = (const float*)d_in[0];
    const float* normal = (const float*)d_in[1];
    const float* albedo = (const float*)d_in[2];
    float* out          = (float*)d_out;
    float* ws           = (float*)d_ws;

    const int B = in_sizes[0] / (HDR_H * HDR_W * 3);         // = 2

    build_tab_kernel<<<dim3(B), 256, 0, stream>>>(env, ws, B);

    const float4* dirs = (const float4*)ws;
    const float2* hs   = (const float2*)(ws + (size_t)B * NPAIR * 4);
    const float*  Wmat = ws + (size_t)B * NPAIR * 6;

    dim3 grid(HW / (BLOCK * PPT), B);                        // (256, B)
    env_render_kernel<<<grid, BLOCK, 0, stream>>>(normal, albedo, dirs, hs, Wmat, out);
}

// Round 4
// 25.366 us; speedup vs baseline: 2.6381x; 1.2521x over previous
//
#include <hip/hip_runtime.h>
#include <math.h>

// out[b,c,y,x] = (1/50)*albedo * sum_m relu(n.l_m)*env*sin(phi_i)
// Pairing: (i,j)<->(16-i,(j+16)&31) antipodal, same sin(phi) coeff:
//   light = n.W + sum_{pairs} |n.l_p| * hs_p        (scale 0.5/50 folded in)
// Factorized dot: n.l(i,j) = sp_i*(nx*st_j - nz*ct_j) + ny*cp_i, trig = constexpr.
// hs table (env-dependent) lives in SGPRs via explicit s_load_dwordx16:
// the accumulate FMAs use h as their one SGPR operand -> no LDS/VMEM in loop.

constexpr int HW    = 512 * 512;
constexpr int BLOCK = 256;

// sin/cos(k*pi/16)
__device__ constexpr float SP[8] = {
    0.195090322f, 0.382683432f, 0.555570233f, 0.707106781f,
    0.831469612f, 0.923879533f, 0.980785280f, 1.0f };
__device__ constexpr float CP[8] = {
    0.980785280f, 0.923879533f, 0.831469612f, 0.707106781f,
    0.555570233f, 0.382683432f, 0.195090322f, 0.0f };
__device__ constexpr float ST[32] = {
    0.0f,          0.195090322f,  0.382683432f,  0.555570233f,
    0.707106781f,  0.831469612f,  0.923879533f,  0.980785280f,
    1.0f,          0.980785280f,  0.923879533f,  0.831469612f,
    0.707106781f,  0.555570233f,  0.382683432f,  0.195090322f,
    0.0f,         -0.195090322f, -0.382683432f, -0.555570233f,
   -0.707106781f, -0.831469612f, -0.923879533f, -0.980785280f,
   -1.0f,         -0.980785280f, -0.923879533f, -0.831469612f,
   -0.707106781f, -0.555570233f, -0.382683432f, -0.195090322f };
__device__ constexpr float CT[32] = {
    1.0f,          0.980785280f,  0.923879533f,  0.831469612f,
    0.707106781f,  0.555570233f,  0.382683432f,  0.195090322f,
    0.0f,         -0.195090322f, -0.382683432f, -0.555570233f,
   -0.707106781f, -0.831469612f, -0.923879533f, -0.980785280f,
   -1.0f,         -0.980785280f, -0.923879533f, -0.831469612f,
   -0.707106781f, -0.555570233f, -0.382683432f, -0.195090322f,
    0.0f,          0.195090322f,  0.382683432f,  0.555570233f,
    0.707106781f,  0.831469612f,  0.923879533f,  0.980785280f };

typedef float f32x16 __attribute__((ext_vector_type(16)));

__device__ __forceinline__ void sload32(const float* p, f32x16& a, f32x16& b) {
    asm volatile("s_load_dwordx16 %0, %2, 0x0\n\t"
                 "s_load_dwordx16 %1, %2, 0x40"
                 : "=&s"(a), "=&s"(b) : "s"(p));
}
__device__ __forceinline__ void swait(f32x16& a, f32x16& b) {
    // tie outputs so uses can't be hoisted above the wait (rule #18)
    asm volatile("s_waitcnt lgkmcnt(0)" : "+s"(a), "+s"(b));
}

__global__ __launch_bounds__(256)
void build_tab_kernel(const float* __restrict__ env, float* __restrict__ ws, int B)
{
    const int b = blockIdx.x;
    const int t = threadIdx.x;          // 256 threads = 32 j x 8 i-slots
    const int iidx = t & 7, j = t >> 3;
    const int i = iidx + 1;
    float4* tab  = (float4*)ws;                         // [B][32][8]
    float*  Wout = ws + (size_t)B * 256 * 4;            // [B][9]

    __shared__ float Wred[4][9];
    float W[9];
    #pragma unroll
    for (int q = 0; q < 9; ++q) W[q] = 0.0f;

    float4 hv = make_float4(0.f, 0.f, 0.f, 0.f);
    if (!(i == 8 && j >= 16)) {                          // row-8 pairs only j<16
        const int i2 = 16 - i, j2 = (j + 16) & 31;
        const float phi   = (float)i * 0.19634954084936207f;   // pi/16
        const float theta = (float)j * 0.19634954084936207f;
        const float sp = sinf(phi),   cp = cosf(phi);
        const float st = sinf(theta), ct = cosf(theta);
        const float dx = st * sp, dy = cp, dz = -ct * sp;      // |l| = 1
        const float scale = sp * 0.01f;                        // sin(phi)*0.5/50
        const float* ea = env + ((size_t)(b * 16 + i ) * 32 + j ) * 3;
        const float* eb = env + ((size_t)(b * 16 + i2) * 32 + j2) * 3;
        hv = make_float4((ea[0] + eb[0]) * scale,
                         (ea[1] + eb[1]) * scale,
                         (ea[2] + eb[2]) * scale, 0.f);
        const float hd0 = (ea[0] - eb[0]) * scale;
        const float hd1 = (ea[1] - eb[1]) * scale;
        const float hd2 = (ea[2] - eb[2]) * scale;
        W[0] = dx * hd0; W[1] = dx * hd1; W[2] = dx * hd2;
        W[3] = dy * hd0; W[4] = dy * hd1; W[5] = dy * hd2;
        W[6] = dz * hd0; W[7] = dz * hd1; W[8] = dz * hd2;
    }
    tab[(size_t)b * 256 + j * 8 + iidx] = hv;

    #pragma unroll
    for (int q = 0; q < 9; ++q) {
        float v = W[q];
        #pragma unroll
        for (int off = 32; off > 0; off >>= 1) v += __shfl_down(v, off);
        if ((t & 63) == 0) Wred[t >> 6][q] = v;
    }
    __syncthreads();
    if (t < 9) Wout[b * 9 + t] = Wred[0][t] + Wred[1][t] + Wred[2][t] + Wred[3][t];
}

__global__ __launch_bounds__(BLOCK)
void env_render_kernel(const float* __restrict__ normal,
                       const float* __restrict__ albedo,
                       const float4* __restrict__ tab,   // [B][32][8]
                       const float* __restrict__ Wmat,   // [B][9]
                       float* __restrict__ out)
{
    const int b   = blockIdx.y;
    const int pix = blockIdx.x * BLOCK + threadIdx.x;

    const float* p = normal + ((size_t)b * HW + pix) * 3;
    const float nx = fmaf(p[2], 2.0f, -1.0f);            // channel flip + decode
    const float ny = fmaf(p[1], 2.0f, -1.0f);
    const float nz = fmaf(p[0], 2.0f, -1.0f);

    const size_t base = (size_t)b * 3 * HW + pix;        // albedo prefetch (early issue)
    const float al0 = albedo[base];
    const float al1 = albedo[base + HW];
    const float al2 = albedo[base + 2 * HW];

    float Wl[9];
    #pragma unroll
    for (int q = 0; q < 9; ++q) Wl[q] = Wmat[b * 9 + q];

    float nyc[8];
    #pragma unroll
    for (int i = 0; i < 8; ++i) nyc[i] = ny * CP[i];

    float s0 = 0.f, s1 = 0.f, s2 = 0.f;
    const float4* tb = tab + (size_t)b * 256;

    #pragma unroll
    for (int j = 0; j < 32; ++j) {
        f32x16 h0, h1;
        sload32((const float*)(tb + j * 8), h0, h1);
        const float u = fmaf(nx, ST[j], -nz * CT[j]);    // overlaps SMEM latency
        swait(h0, h1);
        #pragma unroll
        for (int i = 0; i < 4; ++i) {                    // i-slots 0..3 from h0
            const float d = fmaf(SP[i], u, nyc[i]);
            const float a = fabsf(d);
            s0 = fmaf(a, h0[i * 4 + 0], s0);
            s1 = fmaf(a, h0[i * 4 + 1], s1);
            s2 = fmaf(a, h0[i * 4 + 2], s2);
        }
        #pragma unroll
        for (int i = 0; i < 4; ++i) {                    // i-slots 4..7 from h1
            const float d = fmaf(SP[i + 4], u, nyc[i + 4]);
            const float a = fabsf(d);
            s0 = fmaf(a, h1[i * 4 + 0], s0);
            s1 = fmaf(a, h1[i * 4 + 1], s1);
            s2 = fmaf(a, h1[i * 4 + 2], s2);
        }
    }

    const float l0 = s0 + fmaf(nx, Wl[0], fmaf(ny, Wl[3], nz * Wl[6]));
    const float l1 = s1 + fmaf(nx, Wl[1], fmaf(ny, Wl[4], nz * Wl[7]));
    const float l2 = s2 + fmaf(nx, Wl[2], fmaf(ny, Wl[5], nz * Wl[8]));
    out[base]          = l0 * al0;
    out[base + HW]     = l1 * al1;
    out[base + 2 * HW] = l2 * al2;
}

extern "C" void kernel_launch(void* const* d_in, const int* in_sizes, int n_in,
                              void* d_out, int out_size, void* d_ws, size_t ws_size,
                              hipStream_t stream)
{
    const float* env    = (const float*)d_in[0];
    const float* normal = (const float*)d_in[1];
    const float* albedo = (const float*)d_in[2];
    float* out          = (float*)d_out;
    float* ws           = (float*)d_ws;

    const int B = in_sizes[0] / (16 * 32 * 3);           // = 2

    build_tab_kernel<<<dim3(B), 256, 0, stream>>>(env, ws, B);

    const float4* tab  = (const float4*)ws;
    const float*  Wmat = ws + (size_t)B * 256 * 4;

    dim3 grid(HW / BLOCK, B);                            // (1024, 2)
    env_render_kernel<<<grid, BLOCK, 0, stream>>>(normal, albedo, tab, Wmat, out);
}